// Round 15
// baseline (577.559 us; speedup 1.0000x reference)
//
#include <hip/hip_runtime.h>
#include <hip/hip_bf16.h>
#include <math.h>

#define T_LEN 2048
#define EMB   512
#define NHEAD 8
#define HDIM  64
#define BHEADS 32
#define USEL  40

// ---------------------------------------------------------------------------
// Kernel A: fused QKV projection (fp32 VALU GEMM), N merged across q/k/v.
// Y[8192,1536] = X @ [Wq;Wk;Wv]^T. BM=128 x BN=192, BK=32, 256 thr, 8x12/thr.
// Wt stride 192 (16B-aligned reads; 194 broke b128 alignment -> r14 regression).
// W-staging uses LINEAR map (c4=u/192, nn=u%192): write banks = 64 consecutive
// nn mod 32 -> 2 lanes/bank (free, m136). Reads: (4tj+off) mod 32 -> 2-way free.
// fmaf chain ascending k 0..511 -> q/k/v bitwise identical -> top-k unchanged.
// ---------------------------------------------------------------------------
__global__ __launch_bounds__(256, 2)
void qkv_proj_kernel(const float* __restrict__ X,
                     const float* __restrict__ Wq, const float* __restrict__ bq,
                     const float* __restrict__ Wk, const float* __restrict__ bk,
                     const float* __restrict__ Wv, const float* __restrict__ bv,
                     float* __restrict__ qo, float* __restrict__ ko, float* __restrict__ vo)
{
    alignas(16) __shared__ float Xs[32 * 128];   // [k][m]
    alignas(16) __shared__ float Wt[32 * 192];   // [k][n]

    const int tid = threadIdx.x;
    const int m0 = blockIdx.x * 128;
    const int n0 = blockIdx.y * 192;             // global n in [0,1536)
    const int ti = tid >> 4, tj = tid & 15;

    float acc[8][12];
    #pragma unroll
    for (int i = 0; i < 8; ++i)
        #pragma unroll
        for (int j = 0; j < 12; ++j) acc[i][j] = 0.0f;

    for (int kc = 0; kc < EMB; kc += 32) {
        __syncthreads();
        #pragma unroll
        for (int s = 0; s < 4; ++s) {
            int u = tid + 256 * s;          // 0..1023
            int mm = u & 127, c4 = u >> 7;  // c4: 0..7
            float4 f = *(const float4*)&X[(m0 + mm) * EMB + kc + c4 * 4];
            Xs[(c4 * 4 + 0) * 128 + mm] = f.x;
            Xs[(c4 * 4 + 1) * 128 + mm] = f.y;
            Xs[(c4 * 4 + 2) * 128 + mm] = f.z;
            Xs[(c4 * 4 + 3) * 128 + mm] = f.w;
        }
        #pragma unroll
        for (int s = 0; s < 6; ++s) {
            int u = tid + 256 * s;          // 0..1535
            int c4 = u / 192;               // 0..7 (magic-multiply)
            int nn = u - c4 * 192;          // 0..191; wave: 64 consecutive mod 192
            int ng = n0 + nn;
            int z = ng >> 9, nr = ng & 511;
            const float* Wp = (z == 0) ? Wq : ((z == 1) ? Wk : Wv);
            float4 g = *(const float4*)&Wp[nr * EMB + kc + c4 * 4];
            Wt[(c4 * 4 + 0) * 192 + nn] = g.x;
            Wt[(c4 * 4 + 1) * 192 + nn] = g.y;
            Wt[(c4 * 4 + 2) * 192 + nn] = g.z;
            Wt[(c4 * 4 + 3) * 192 + nn] = g.w;
        }
        __syncthreads();

        #pragma unroll 2
        for (int k = 0; k < 32; ++k) {
            float4 xa = *(const float4*)&Xs[k * 128 + ti * 8];
            float4 xb = *(const float4*)&Xs[k * 128 + ti * 8 + 4];
            float4 wa = *(const float4*)&Wt[k * 192 + tj * 4];
            float4 wb = *(const float4*)&Wt[k * 192 + 64 + tj * 4];
            float4 wc = *(const float4*)&Wt[k * 192 + 128 + tj * 4];
            float xv[8]  = {xa.x, xa.y, xa.z, xa.w, xb.x, xb.y, xb.z, xb.w};
            float wv[12] = {wa.x, wa.y, wa.z, wa.w, wb.x, wb.y, wb.z, wb.w,
                            wc.x, wc.y, wc.z, wc.w};
            #pragma unroll
            for (int i = 0; i < 8; ++i)
                #pragma unroll
                for (int j = 0; j < 12; ++j)
                    acc[i][j] = fmaf(xv[i], wv[j], acc[i][j]);
        }
    }

    // Epilogue: three n-quads (each fully inside one z and one head).
    #pragma unroll
    for (int qd = 0; qd < 3; ++qd) {
        int n = n0 + qd * 64 + tj * 4;
        int z = n >> 9, nr = n & 511;
        int h = nr >> 6, d = nr & 63;
        const float* bp = (z == 0) ? bq : ((z == 1) ? bk : bv);
        float* dp = (z == 0) ? qo : ((z == 1) ? ko : vo);
        float sc = (z == 0) ? 0.125f : 1.0f;
        float4 bf = *(const float4*)&bp[nr];
        #pragma unroll
        for (int i = 0; i < 8; ++i) {
            int m = m0 + ti * 8 + i;
            int b = m >> 11, t = m & 2047;
            float4 v4;
            v4.x = (acc[i][qd * 4 + 0] + bf.x) * sc;
            v4.y = (acc[i][qd * 4 + 1] + bf.y) * sc;
            v4.z = (acc[i][qd * 4 + 2] + bf.z) * sc;
            v4.w = (acc[i][qd * 4 + 3] + bf.w) * sc;
            *(float4*)&dp[((size_t)((b * NHEAD + h) * T_LEN + t)) * HDIM + d] = v4;
        }
    }
}

// ---------------------------------------------------------------------------
// Kernel B1: count[t] = multiplicity of t in index_sample, then compact the
// distinct sampled indices -> klist (padded to x128 with dup of klist[0]).
// ---------------------------------------------------------------------------
__global__ __launch_bounds__(256)
void count_compact_kernel(const int* __restrict__ idxs, int n,
                          int* __restrict__ count, int* __restrict__ klist,
                          int* __restrict__ ncp)
{
    __shared__ int cnt[T_LEN];
    __shared__ int th_tot[256];
    __shared__ int th_off[256];
    __shared__ int ncs;
    const int tid = threadIdx.x;
    for (int j = tid; j < T_LEN; j += 256) cnt[j] = 0;
    __syncthreads();
    for (int i = tid; i < n; i += 256) atomicAdd(&cnt[idxs[i] & (T_LEN - 1)], 1);
    __syncthreads();
    const int base = tid * 8;
    int flags[8]; int loc = 0;
    #pragma unroll
    for (int j = 0; j < 8; ++j) {
        int c = cnt[base + j];
        count[base + j] = c;
        flags[j] = (c > 0); loc += flags[j];
    }
    th_tot[tid] = loc;
    __syncthreads();
    if (tid == 0) {
        int run = 0;
        for (int i = 0; i < 256; ++i) { th_off[i] = run; run += th_tot[i]; }
        ncs = run;
        ncp[0] = run;
    }
    __syncthreads();
    int off = th_off[tid];
    #pragma unroll
    for (int j = 0; j < 8; ++j)
        if (flags[j]) klist[off++] = base + j;
    __syncthreads();
    const int nc = ncs;
    const int nt = (nc + 127) & ~127;
    const int k0 = klist[0];
    for (int j = nc + tid; j < nt; j += 256) klist[j] = k0;
}

// ---------------------------------------------------------------------------
// Kernel B2a: partial ksum/vsum per (bh, slice). Coalesced float4 streaming.
// ---------------------------------------------------------------------------
__global__ __launch_bounds__(256)
void ksum_vmean_part_kernel(const int* __restrict__ count,
                            const float* __restrict__ k, const float* __restrict__ v,
                            float* __restrict__ kpart, float* __restrict__ vpart)
{
    __shared__ int cs[256];
    alignas(16) __shared__ float rk[16 * 64];
    alignas(16) __shared__ float rv[16 * 64];

    const int sl = blockIdx.x, bh = blockIdx.y, tid = threadIdx.x;
    const int f4 = tid & 15, tg = tid >> 4;
    const int t0 = sl * 256;

    cs[tid] = count[t0 + tid];
    __syncthreads();

    const float4* k4 = (const float4*)(k + (size_t)bh * T_LEN * HDIM) + t0 * 16;
    const float4* v4 = (const float4*)(v + (size_t)bh * T_LEN * HDIM) + t0 * 16;

    float4 ak = {0.f, 0.f, 0.f, 0.f}, av = {0.f, 0.f, 0.f, 0.f};
    #pragma unroll
    for (int s = 0; s < 16; ++s) {
        int t = tg + s * 16;
        float c = (float)cs[t];
        float4 kf = k4[t * 16 + f4];
        float4 vf = v4[t * 16 + f4];
        ak.x = fmaf(c, kf.x, ak.x); ak.y = fmaf(c, kf.y, ak.y);
        ak.z = fmaf(c, kf.z, ak.z); ak.w = fmaf(c, kf.w, ak.w);
        av.x += vf.x; av.y += vf.y; av.z += vf.z; av.w += vf.w;
    }
    *(float4*)&rk[tg * 64 + f4 * 4] = ak;
    *(float4*)&rv[tg * 64 + f4 * 4] = av;
    __syncthreads();

    if (tid < 64) {
        float sk = 0.f, sv = 0.f;
        #pragma unroll
        for (int g = 0; g < 16; ++g) { sk += rk[g * 64 + tid]; sv += rv[g * 64 + tid]; }
        kpart[((size_t)bh * 8 + sl) * 64 + tid] = sk;
        vpart[((size_t)bh * 8 + sl) * 64 + tid] = sv;
    }
}

// ---------------------------------------------------------------------------
// Kernel B2b: reduce 8 slice-partials -> ksum[bh][d], vmean[bh][d].
// ---------------------------------------------------------------------------
__global__ __launch_bounds__(64)
void ksum_vmean_reduce_kernel(const float* __restrict__ kpart, const float* __restrict__ vpart,
                              float* __restrict__ ksum, float* __restrict__ vmean)
{
    const int bh = blockIdx.x, d = threadIdx.x;
    float sk = 0.f, sv = 0.f;
    #pragma unroll
    for (int sl = 0; sl < 8; ++sl) {
        sk += kpart[((size_t)bh * 8 + sl) * 64 + d];
        sv += vpart[((size_t)bh * 8 + sl) * 64 + d];
    }
    ksum[bh * 64 + d]  = sk;
    vmean[bh * 64 + d] = sv * (1.0f / 2048.0f);
}

// ---------------------------------------------------------------------------
// Kernel C: sparsity scan over compacted sampled keys (fp32, 128x128 tile).
// ---------------------------------------------------------------------------
__global__ __launch_bounds__(256)
void sparsity_scan_kernel(const float* __restrict__ q, const float* __restrict__ k,
                          const float* __restrict__ ksum, const int* __restrict__ klist,
                          const int* __restrict__ ncp, float* __restrict__ spars)
{
    alignas(16) __shared__ float qs[64 * 128];   // [d][qq]
    alignas(16) __shared__ float ks[64 * 128];   // [d][kk] (reused as reduce buf)
    __shared__ float ksm[64];

    const int tid = threadIdx.x;
    const int bh = blockIdx.y;
    const int q0 = blockIdx.x * 128;
    const int ti = tid >> 4, tj = tid & 15;

    const float* qb = q + ((size_t)bh * T_LEN + q0) * HDIM;
    const float* kb = k + (size_t)bh * T_LEN * HDIM;
    const int ntiles = (ncp[0] + 127) >> 7;

    #pragma unroll
    for (int s = 0; s < 8; ++s) {
        int u = tid + 256 * s;
        int qq = u & 127, c4 = u >> 7;
        float4 f = *(const float4*)&qb[qq * HDIM + c4 * 4];
        qs[(c4 * 4 + 0) * 128 + qq] = f.x;
        qs[(c4 * 4 + 1) * 128 + qq] = f.y;
        qs[(c4 * 4 + 2) * 128 + qq] = f.z;
        qs[(c4 * 4 + 3) * 128 + qq] = f.w;
    }
    if (tid < 64) ksm[tid] = ksum[bh * 64 + tid];

    float vmax[8];
    #pragma unroll
    for (int i = 0; i < 8; ++i) vmax[i] = -INFINITY;

    for (int kt = 0; kt < ntiles; ++kt) {
        __syncthreads();
        #pragma unroll
        for (int s = 0; s < 8; ++s) {
            int u = tid + 256 * s;
            int kk = u & 127, c4 = u >> 7;
            int row = klist[kt * 128 + kk];
            float4 f = *(const float4*)&kb[row * HDIM + c4 * 4];
            ks[(c4 * 4 + 0) * 128 + kk] = f.x;
            ks[(c4 * 4 + 1) * 128 + kk] = f.y;
            ks[(c4 * 4 + 2) * 128 + kk] = f.z;
            ks[(c4 * 4 + 3) * 128 + kk] = f.w;
        }
        __syncthreads();

        float dot[8][8];
        #pragma unroll
        for (int i = 0; i < 8; ++i)
            #pragma unroll
            for (int j = 0; j < 8; ++j) dot[i][j] = 0.0f;

        #pragma unroll 4
        for (int d = 0; d < 64; ++d) {
            float4 qa = *(const float4*)&qs[d * 128 + ti * 8];
            float4 qc = *(const float4*)&qs[d * 128 + ti * 8 + 4];
            float4 ka = *(const float4*)&ks[d * 128 + tj * 4];        // strided
            float4 kc = *(const float4*)&ks[d * 128 + 64 + tj * 4];   // conflict-free
            float qv[8] = {qa.x, qa.y, qa.z, qa.w, qc.x, qc.y, qc.z, qc.w};
            float kv[8] = {ka.x, ka.y, ka.z, ka.w, kc.x, kc.y, kc.z, kc.w};
            #pragma unroll
            for (int i = 0; i < 8; ++i)
                #pragma unroll
                for (int j = 0; j < 8; ++j)
                    dot[i][j] = fmaf(qv[i], kv[j], dot[i][j]);
        }
        #pragma unroll
        for (int i = 0; i < 8; ++i) {
            float m8 = dot[i][0];
            #pragma unroll
            for (int j = 1; j < 8; ++j) m8 = fmaxf(m8, dot[i][j]);
            vmax[i] = fmaxf(vmax[i], m8);
        }
    }
    __syncthreads();

    float* red = ks;
    #pragma unroll
    for (int i = 0; i < 8; ++i) red[(ti * 8 + i) * 17 + tj] = vmax[i];
    __syncthreads();
    if (tid < 128) {
        float m = red[tid * 17];
        #pragma unroll
        for (int j = 1; j < 16; ++j) m = fmaxf(m, red[tid * 17 + j]);
        float sdot = 0.f;
        #pragma unroll
        for (int d = 0; d < 64; ++d) sdot = fmaf(qs[d * 128 + tid], ksm[d], sdot);
        spars[bh * T_LEN + q0 + tid] = m - sdot * (1.0f / 2048.0f);
    }
}

// ---------------------------------------------------------------------------
// Kernel D: top-40 per bh by iterative argmax (ties -> smaller index).
// ---------------------------------------------------------------------------
__global__ __launch_bounds__(256)
void topk_kernel(const float* __restrict__ spars, int* __restrict__ topi)
{
    __shared__ float vals[T_LEN];
    __shared__ float rv[256];
    __shared__ int   ri[256];
    const int bh = blockIdx.x, tid = threadIdx.x;
    for (int j = tid; j < T_LEN; j += 256) vals[j] = spars[bh * T_LEN + j];
    __syncthreads();
    for (int it = 0; it < USEL; ++it) {
        float bv = -INFINITY; int bi = 0;
        #pragma unroll
        for (int jj = 0; jj < 8; ++jj) {
            int j = tid * 8 + jj;
            float vv = vals[j];
            if (vv > bv) { bv = vv; bi = j; }
        }
        rv[tid] = bv; ri[tid] = bi;
        __syncthreads();
        for (int s = 128; s > 0; s >>= 1) {
            if (tid < s) {
                float ov = rv[tid + s]; int oi = ri[tid + s];
                if (ov > rv[tid] || (ov == rv[tid] && oi < ri[tid])) { rv[tid] = ov; ri[tid] = oi; }
            }
            __syncthreads();
        }
        if (tid == 0) {
            int win = ri[0] & (T_LEN - 1);
            topi[bh * USEL + it] = win;
            vals[win] = -INFINITY;
        }
        __syncthreads();
    }
}

// ---------------------------------------------------------------------------
// Kernel E1: gather selected q rows -> qsel[bh][u][d]. (q dead afterwards)
// ---------------------------------------------------------------------------
__global__ __launch_bounds__(256)
void gather_q_kernel(const float* __restrict__ q, const int* __restrict__ topi,
                     float* __restrict__ qsel)
{
    const int bh = blockIdx.x, tid = threadIdx.x;
    for (int i = tid; i < USEL * HDIM; i += 256) {
        int u = i >> 6, d = i & 63;
        int t = topi[bh * USEL + u] & (T_LEN - 1);
        qsel[(size_t)bh * USEL * HDIM + i] = q[((size_t)bh * T_LEN + t) * HDIM + d];
    }
}

// ---------------------------------------------------------------------------
// Kernel E2: S[bh][u][t] = qsel[bh][u] . k[bh][t]. Grid (8 t-slices, 32 bh).
// ---------------------------------------------------------------------------
__global__ __launch_bounds__(256)
void sel_scores_kernel(const float* __restrict__ qsel, const float* __restrict__ k,
                       float* __restrict__ S)
{
    __shared__ float qsT[64 * 41];    // [d][u] stride 41
    __shared__ float ksT[64 * 257];   // [d][t] stride 257

    const int sl = blockIdx.x, bh = blockIdx.y, tid = threadIdx.x;
    const int t0 = sl * 256;

    for (int i = tid; i < USEL * HDIM; i += 256) {
        int u = i >> 6, d = i & 63;
        qsT[d * 41 + u] = qsel[(size_t)bh * USEL * HDIM + i];
    }
    const float4* k4 = (const float4*)(k + (size_t)bh * T_LEN * HDIM);
    #pragma unroll
    for (int s = 0; s < 16; ++s) {
        int u = tid + 256 * s;          // 0..4095
        int c4 = u & 15, t = u >> 4;    // t 0..255
        float4 f = k4[(t0 + t) * 16 + c4];
        ksT[(c4 * 4 + 0) * 257 + t] = f.x;
        ksT[(c4 * 4 + 1) * 257 + t] = f.y;
        ksT[(c4 * 4 + 2) * 257 + t] = f.z;
        ksT[(c4 * 4 + 3) * 257 + t] = f.w;
    }
    __syncthreads();

    const int qg = tid >> 5;   // 0..7 -> 5 queries each
    const int kg = tid & 31;   // strided keys: kg + 32*j

    float acc[5][8];
    #pragma unroll
    for (int i = 0; i < 5; ++i)
        #pragma unroll
        for (int j = 0; j < 8; ++j) acc[i][j] = 0.0f;

    #pragma unroll 4
    for (int d = 0; d < 64; ++d) {
        float qv[5], kv[8];
        #pragma unroll
        for (int i = 0; i < 5; ++i) qv[i] = qsT[d * 41 + qg * 5 + i];
        #pragma unroll
        for (int j = 0; j < 8; ++j) kv[j] = ksT[d * 257 + kg + 32 * j];
        #pragma unroll
        for (int i = 0; i < 5; ++i)
            #pragma unroll
            for (int j = 0; j < 8; ++j)
                acc[i][j] = fmaf(qv[i], kv[j], acc[i][j]);
    }

    #pragma unroll
    for (int i = 0; i < 5; ++i) {
        float* sp = &S[((size_t)bh * USEL + qg * 5 + i) * T_LEN + t0 + kg];
        #pragma unroll
        for (int j = 0; j < 8; ++j) sp[32 * j] = acc[i][j];
    }
}

// ---------------------------------------------------------------------------
// Kernel E3: in-place softmax over each S row (1280 rows of 2048).
// ---------------------------------------------------------------------------
__global__ __launch_bounds__(256)
void sel_softmax_kernel(float* __restrict__ S)
{
    __shared__ float red[256];
    const int row = blockIdx.x, tid = threadIdx.x;
    float* sr = S + (size_t)row * T_LEN;

    float x[8];
    float m = -INFINITY;
    #pragma unroll
    for (int s = 0; s < 8; ++s) { x[s] = sr[tid + 256 * s]; m = fmaxf(m, x[s]); }
    red[tid] = m;
    __syncthreads();
    for (int s = 128; s > 0; s >>= 1) {
        if (tid < s) red[tid] = fmaxf(red[tid], red[tid + s]);
        __syncthreads();
    }
    m = red[0];
    __syncthreads();

    float sum = 0.f;
    #pragma unroll
    for (int s = 0; s < 8; ++s) { x[s] = __expf(x[s] - m); sum += x[s]; }
    red[tid] = sum;
    __syncthreads();
    for (int s = 128; s > 0; s >>= 1) {
        if (tid < s) red[tid] += red[tid + s];
        __syncthreads();
    }
    float inv = 1.0f / red[0];
    #pragma unroll
    for (int s = 0; s < 8; ++s) sr[tid + 256 * s] = x[s] * inv;
}

// ---------------------------------------------------------------------------
// Kernel E4: PV partial. Grid (16 t-slices, 32 bh).
// ---------------------------------------------------------------------------
__global__ __launch_bounds__(256)
void pv_part_kernel(const float* __restrict__ S, const float* __restrict__ v,
                    float* __restrict__ part)
{
    __shared__ float ps[USEL * 128];      // [q][t]
    __shared__ float vs[128 * 69];        // [t][d] stride 69
    __shared__ float obuf[128 * 20];

    const int sl = blockIdx.x, bh = blockIdx.y, tid = threadIdx.x;
    const int t0 = sl * 128;

    for (int i = tid; i < USEL * 128; i += 256) {
        int q = i >> 7, t = i & 127;
        ps[q * 128 + t] = S[((size_t)bh * USEL + q) * T_LEN + t0 + t];
    }
    const float4* v4 = (const float4*)(v + (size_t)bh * T_LEN * HDIM);
    #pragma unroll
    for (int s = 0; s < 8; ++s) {
        int u = tid + 256 * s;          // 0..2047
        int c4 = u & 15, t = u >> 4;    // t 0..127
        float4 f = v4[(t0 + t) * 16 + c4];
        vs[t * 69 + c4 * 4 + 0] = f.x;
        vs[t * 69 + c4 * 4 + 1] = f.y;
        vs[t * 69 + c4 * 4 + 2] = f.z;
        vs[t * 69 + c4 * 4 + 3] = f.w;
    }
    __syncthreads();

    const int qg = tid >> 5, r = tid & 31;
    const int dg = r >> 1, th = r & 1;
    const int tb = th * 64;

    float o[5][4];
    #pragma unroll
    for (int i = 0; i < 5; ++i)
        #pragma unroll
        for (int j = 0; j < 4; ++j) o[i][j] = 0.0f;

    #pragma unroll 4
    for (int tt = 0; tt < 64; ++tt) {
        int t = tb + tt;
        float pv[5];
        #pragma unroll
        for (int i = 0; i < 5; ++i) pv[i] = ps[(qg * 5 + i) * 128 + t];
        float4 vv = *(const float4*)&vs[t * 69 + dg * 4];
        #pragma unroll
        for (int i = 0; i < 5; ++i) {
            o[i][0] = fmaf(pv[i], vv.x, o[i][0]);
            o[i][1] = fmaf(pv[i], vv.y, o[i][1]);
            o[i][2] = fmaf(pv[i], vv.z, o[i][2]);
            o[i][3] = fmaf(pv[i], vv.w, o[i][3]);
        }
    }

    const int p = qg * 16 + dg;   // 0..127
    if (th == 1) {
        #pragma unroll
        for (int i = 0; i < 5; ++i)
            #pragma unroll
            for (int j = 0; j < 4; ++j) obuf[p * 20 + i * 4 + j] = o[i][j];
    }
    __syncthreads();
    if (th == 0) {
        float* pb = part + ((size_t)bh * 16 + sl) * (USEL * HDIM);
        #pragma unroll
        for (int i = 0; i < 5; ++i)
            #pragma unroll
            for (int j = 0; j < 4; ++j)
                pb[(qg * 5 + i) * HDIM + dg * 4 + j] = o[i][j] + obuf[p * 20 + i * 4 + j];
    }
}

// ---------------------------------------------------------------------------
// Kernel E5: deterministic merge of 16 PV partials -> attn[bh][u][d].
// ---------------------------------------------------------------------------
__global__ __launch_bounds__(256)
void pv_merge_kernel(const float* __restrict__ part, float* __restrict__ attn)
{
    const int bh = blockIdx.x, tid = threadIdx.x;
    for (int i = tid; i < USEL * HDIM; i += 256) {
        float s = 0.f;
        #pragma unroll
        for (int sl = 0; sl < 16; ++sl)
            s += part[((size_t)bh * 16 + sl) * (USEL * HDIM) + i];
        attn[(size_t)bh * USEL * HDIM + i] = s;
    }
}

// ---------------------------------------------------------------------------
// Kernel F1: fill context (B,T,E layout, fp32) with per-head vmean.
// ---------------------------------------------------------------------------
__global__ __launch_bounds__(256)
void ctx_fill_kernel(const float* __restrict__ vmean, float* __restrict__ ctx)
{
    int flat = blockIdx.x * 256 + threadIdx.x;
    int d = flat & 63, h = (flat >> 6) & 7, b = flat >> 20;
    int bh = (b << 3) | h;
    ctx[flat] = vmean[bh * 64 + d];
}

// ---------------------------------------------------------------------------
// Kernel F2: scatter attn rows into context at top_idx positions.
// ---------------------------------------------------------------------------
__global__ void ctx_scatter_kernel(const float* __restrict__ attn, const int* __restrict__ topi,
                                   float* __restrict__ ctx)
{
    const int u = blockIdx.x, bh = blockIdx.y, d = threadIdx.x;
    const int b = bh >> 3, h = bh & 7;
    const int t = topi[bh * USEL + u] & (T_LEN - 1);
    ctx[(size_t)(b * T_LEN + t) * EMB + h * 64 + d] =
        attn[((size_t)bh * USEL + u) * HDIM + d];
}

// ---------------------------------------------------------------------------
// Kernel G: out = ctx @ Wo^T + bo. 128x128/BK32/8x8x256t (round-11 struct).
// ---------------------------------------------------------------------------
__global__ __launch_bounds__(256, 4)
void out_proj_kernel(const float* __restrict__ A, const float* __restrict__ Wo,
                     const float* __restrict__ bo, float* __restrict__ out)
{
    alignas(16) __shared__ float Xs[32 * 128];
    alignas(16) __shared__ float Wt[32 * 128];

    const int tid = threadIdx.x;
    const int m0 = blockIdx.x * 128;
    const int n0 = blockIdx.y * 128;
    const int ti = tid >> 4, tj = tid & 15;

    float acc[8][8];
    #pragma unroll
    for (int i = 0; i < 8; ++i)
        #pragma unroll
        for (int j = 0; j < 8; ++j) acc[i][j] = 0.0f;

    for (int kc = 0; kc < EMB; kc += 32) {
        __syncthreads();
        #pragma unroll
        for (int s = 0; s < 4; ++s) {
            int u = tid + 256 * s;
            int mm = u & 127, c4 = u >> 7;
            float4 f = *(const float4*)&A[(m0 + mm) * EMB + kc + c4 * 4];
            Xs[(c4 * 4 + 0) * 128 + mm] = f.x;
            Xs[(c4 * 4 + 1) * 128 + mm] = f.y;
            Xs[(c4 * 4 + 2) * 128 + mm] = f.z;
            Xs[(c4 * 4 + 3) * 128 + mm] = f.w;
            float4 g = *(const float4*)&Wo[(n0 + mm) * EMB + kc + c4 * 4];
            Wt[(c4 * 4 + 0) * 128 + mm] = g.x;
            Wt[(c4 * 4 + 1) * 128 + mm] = g.y;
            Wt[(c4 * 4 + 2) * 128 + mm] = g.z;
            Wt[(c4 * 4 + 3) * 128 + mm] = g.w;
        }
        __syncthreads();

        #pragma unroll 4
        for (int k = 0; k < 32; ++k) {
            float4 xa = *(const float4*)&Xs[k * 128 + ti * 8];
            float4 xb = *(const float4*)&Xs[k * 128 + ti * 8 + 4];
            float4 wa = *(const float4*)&Wt[k * 128 + tj * 4];
            float4 wb = *(const float4*)&Wt[k * 128 + 64 + tj * 4];
            float xv[8] = {xa.x, xa.y, xa.z, xa.w, xb.x, xb.y, xb.z, xb.w};
            float wv[8] = {wa.x, wa.y, wa.z, wa.w, wb.x, wb.y, wb.z, wb.w};
            #pragma unroll
            for (int i = 0; i < 8; ++i)
                #pragma unroll
                for (int j = 0; j < 8; ++j)
                    acc[i][j] = fmaf(xv[i], wv[j], acc[i][j]);
        }
    }

    const int na = n0 + tj * 4;
    const int nb = n0 + 64 + tj * 4;
    float4 bfa = *(const float4*)&bo[na];
    float4 bfb = *(const float4*)&bo[nb];
    #pragma unroll
    for (int i = 0; i < 8; ++i) {
        int m = m0 + ti * 8 + i;
        float4 v0, v1;
        v0.x = acc[i][0] + bfa.x; v0.y = acc[i][1] + bfa.y;
        v0.z = acc[i][2] + bfa.z; v0.w = acc[i][3] + bfa.w;
        v1.x = acc[i][4] + bfb.x; v1.y = acc[i][5] + bfb.y;
        v1.z = acc[i][6] + bfb.z; v1.w = acc[i][7] + bfb.w;
        *(float4*)&out[(size_t)m * EMB + na] = v0;
        *(float4*)&out[(size_t)m * EMB + nb] = v1;
    }
}

// ---------------------------------------------------------------------------
// Diagnostic: if ws_size is too small, report it via d_out (absmax ~= MiB).
// ---------------------------------------------------------------------------
__global__ __launch_bounds__(256)
void ws_diag_kernel(float* __restrict__ out, int n, float mib)
{
    int flat = blockIdx.x * 256 + threadIdx.x;
    if (flat < n) out[flat] = mib;
}

// ---------------------------------------------------------------------------
extern "C" void kernel_launch(void* const* d_in, const int* in_sizes, int n_in,
                              void* d_out, int out_size, void* d_ws, size_t ws_size,
                              hipStream_t stream)
{
    // fp32 inputs/outputs in dict order (confirmed). Bind by size; same-size
    // tensors in encounter (=dict) order: Wq, Wk, Wv, Wo.
    const float* X = nullptr; const int* idxs = nullptr;
    const float* Wseen[4] = {nullptr, nullptr, nullptr, nullptr};
    const float* bseen[4] = {nullptr, nullptr, nullptr, nullptr};
    int nw = 0, nb = 0, u_part = 2048;
    for (int i = 0; i < n_in; ++i) {
        int sz = in_sizes[i];
        if (sz == EMB * EMB * 16) { if (!X) X = (const float*)d_in[i]; }
        else if (sz == T_LEN)     { if (!idxs) { idxs = (const int*)d_in[i]; u_part = sz; } }
        else if (sz == EMB * EMB) { if (nw < 4) Wseen[nw++] = (const float*)d_in[i]; }
        else if (sz == EMB)       { if (nb < 4) bseen[nb++] = (const float*)d_in[i]; }
    }
    if (!X || !idxs || nw < 4 || nb < 4) {
        X = (const float*)d_in[0]; idxs = (const int*)d_in[1];
        Wseen[0] = (const float*)d_in[2]; bseen[0] = (const float*)d_in[3];
        Wseen[1] = (const float*)d_in[4]; bseen[1] = (const float*)d_in[5];
        Wseen[2] = (const float*)d_in[6]; bseen[2] = (const float*)d_in[7];
        Wseen[3] = (const float*)d_in[8]; bseen[3] = (const float*)d_in[9];
        u_part = in_sizes[1];
    }
    const float *Wq = Wseen[0], *Wk = Wseen[1], *Wv = Wseen[2], *Wo = Wseen[3];
    const float *bq = bseen[0], *bk = bseen[1], *bv = bseen[2], *bo = bseen[3];

    // Workspace layout (peak 50,951,168 B, unchanged).
    const size_t NEED = 50951168ULL;
    if (ws_size < NEED) {
        ws_diag_kernel<<<(out_size + 255) / 256, 256, 0, stream>>>(
            (float*)d_out, out_size, (float)(ws_size >> 20));
        return;
    }

    float* ws    = (float*)d_ws;
    float* qw    = ws;                    // 4,194,304 floats
    float* kw    = qw + 4194304;
    float* vw    = kw + 4194304;
    float* tail  = vw + 4194304;
    float* slotA = tail;                  // 81920: qsel, later attn
    float* spars = tail + 81920;          // 65536
    int*   count = (int*)(tail + 147456); // 2048
    float* ksum  = tail + 149504;         // 2048
    float* vmean = tail + 151552;         // 2048
    int*   topi  = (int*)(tail + 153600); // 1280
    float* kpart = tail;                  // overlays in slotA (disjoint liveness)
    float* vpart = tail + 16384;
    int*   klist = (int*)(tail + 32768);
    int*   ncp   = (int*)(tail + 34816);
    float* S     = qw;                    // q dead after gather
    float* pvp   = qw + 2621440;
    float* qsel  = slotA;
    float* attn  = slotA;
    float* ctx   = (float*)d_ws;

    qkv_proj_kernel<<<dim3(64, 8), 256, 0, stream>>>(X, Wq, bq, Wk, bk, Wv, bv, qw, kw, vw);
    count_compact_kernel<<<1, 256, 0, stream>>>(idxs, u_part, count, klist, ncp);
    ksum_vmean_part_kernel<<<dim3(8, 32), 256, 0, stream>>>(count, kw, vw, kpart, vpart);
    ksum_vmean_reduce_kernel<<<32, 64, 0, stream>>>(kpart, vpart, ksum, vmean);
    sparsity_scan_kernel<<<dim3(16, 32), 256, 0, stream>>>(qw, kw, ksum, klist, ncp, spars);
    topk_kernel<<<32, 256, 0, stream>>>(spars, topi);
    gather_q_kernel<<<32, 256, 0, stream>>>(qw, topi, qsel);
    // qw dead; S/pvp take over that region.
    sel_scores_kernel<<<dim3(8, 32), 256, 0, stream>>>(qsel, kw, S);
    sel_softmax_kernel<<<1280, 256, 0, stream>>>(S);
    pv_part_kernel<<<dim3(16, 32), 256, 0, stream>>>(S, vw, pvp);
    pv_merge_kernel<<<32, 256, 0, stream>>>(pvp, attn);
    // S/pvp dead; ctx takes over the whole front region.
    ctx_fill_kernel<<<16384, 256, 0, stream>>>(vmean, ctx);
    ctx_scatter_kernel<<<dim3(USEL, BHEADS), 64, 0, stream>>>(attn, topi, ctx);
    out_proj_kernel<<<dim3(64, 4), 256, 0, stream>>>(ctx, Wo, bo, (float*)d_out);
}

// Round 16
// 517.691 us; speedup vs baseline: 1.1156x; 1.1156x over previous
//
#include <hip/hip_runtime.h>
#include <hip/hip_bf16.h>
#include <math.h>

#define T_LEN 2048
#define EMB   512
#define NHEAD 8
#define HDIM  64
#define BHEADS 32
#define USEL  40

typedef __bf16 bf16v8 __attribute__((ext_vector_type(8)));
typedef float f32x4 __attribute__((ext_vector_type(4)));
typedef unsigned short u16;

// Split a float4 into bf16 hi + lo halves, packed as uint2 (4 x u16 each).
__device__ __forceinline__ void cvt4_hilo(const float4 f, uint2& ph, uint2& pl)
{
    __hip_bfloat16 h0 = __float2bfloat16(f.x);
    __hip_bfloat16 h1 = __float2bfloat16(f.y);
    __hip_bfloat16 h2 = __float2bfloat16(f.z);
    __hip_bfloat16 h3 = __float2bfloat16(f.w);
    __hip_bfloat16 l0 = __float2bfloat16(f.x - __bfloat162float(h0));
    __hip_bfloat16 l1 = __float2bfloat16(f.y - __bfloat162float(h1));
    __hip_bfloat16 l2 = __float2bfloat16(f.z - __bfloat162float(h2));
    __hip_bfloat16 l3 = __float2bfloat16(f.w - __bfloat162float(h3));
    ph.x = (unsigned)*(const u16*)&h0 | ((unsigned)*(const u16*)&h1 << 16);
    ph.y = (unsigned)*(const u16*)&h2 | ((unsigned)*(const u16*)&h3 << 16);
    pl.x = (unsigned)*(const u16*)&l0 | ((unsigned)*(const u16*)&l1 << 16);
    pl.y = (unsigned)*(const u16*)&l2 | ((unsigned)*(const u16*)&l3 << 16);
}

// ---------------------------------------------------------------------------
// Kernel A: fused QKV projection (fp32 VALU GEMM) — round-11 geometry (best
// measured: 171 us, 0 conflicts). 128x128 tile, BK=32, 256 thr, 8x8/thread.
// fmaf chain ascending k 0..511 -> q/k/v bitwise identical -> top-k unchanged.
// ---------------------------------------------------------------------------
__global__ __launch_bounds__(256, 4)
void qkv_proj_kernel(const float* __restrict__ X,
                     const float* __restrict__ Wq, const float* __restrict__ bq,
                     const float* __restrict__ Wk, const float* __restrict__ bk,
                     const float* __restrict__ Wv, const float* __restrict__ bv,
                     float* __restrict__ qo, float* __restrict__ ko, float* __restrict__ vo)
{
    alignas(16) __shared__ float Xs[32 * 128];   // [k][m]
    alignas(16) __shared__ float Wt[32 * 128];   // [k][n]

    const int z = blockIdx.z;
    const float* W; const float* bias; float* dst; float scale;
    if (z == 0)      { W = Wq; bias = bq; dst = qo; scale = 0.125f; }
    else if (z == 1) { W = Wk; bias = bk; dst = ko; scale = 1.0f;   }
    else             { W = Wv; bias = bv; dst = vo; scale = 1.0f;   }

    const int tid = threadIdx.x;
    const int m0 = blockIdx.x * 128;
    const int n0 = blockIdx.y * 128;
    const int ti = tid >> 4, tj = tid & 15;

    float acc[8][8];
    #pragma unroll
    for (int i = 0; i < 8; ++i)
        #pragma unroll
        for (int j = 0; j < 8; ++j) acc[i][j] = 0.0f;

    for (int kc = 0; kc < EMB; kc += 32) {
        __syncthreads();
        #pragma unroll
        for (int s = 0; s < 4; ++s) {
            int u = tid + 256 * s;          // 0..1023
            int mm = u & 127, c4 = u >> 7;  // c4: 0..7
            float4 f = *(const float4*)&X[(m0 + mm) * EMB + kc + c4 * 4];
            Xs[(c4 * 4 + 0) * 128 + mm] = f.x;
            Xs[(c4 * 4 + 1) * 128 + mm] = f.y;
            Xs[(c4 * 4 + 2) * 128 + mm] = f.z;
            Xs[(c4 * 4 + 3) * 128 + mm] = f.w;
            float4 g = *(const float4*)&W[(n0 + mm) * EMB + kc + c4 * 4];
            Wt[(c4 * 4 + 0) * 128 + mm] = g.x;
            Wt[(c4 * 4 + 1) * 128 + mm] = g.y;
            Wt[(c4 * 4 + 2) * 128 + mm] = g.z;
            Wt[(c4 * 4 + 3) * 128 + mm] = g.w;
        }
        __syncthreads();

        #pragma unroll 4
        for (int k = 0; k < 32; ++k) {
            float4 xa = *(const float4*)&Xs[k * 128 + ti * 8];
            float4 xb = *(const float4*)&Xs[k * 128 + ti * 8 + 4];
            float4 wa = *(const float4*)&Wt[k * 128 + tj * 4];        // strided
            float4 wb = *(const float4*)&Wt[k * 128 + 64 + tj * 4];   // conflict-free
            float xv[8] = {xa.x, xa.y, xa.z, xa.w, xb.x, xb.y, xb.z, xb.w};
            float wv[8] = {wa.x, wa.y, wa.z, wa.w, wb.x, wb.y, wb.z, wb.w};
            #pragma unroll
            for (int i = 0; i < 8; ++i)
                #pragma unroll
                for (int j = 0; j < 8; ++j)
                    acc[i][j] = fmaf(xv[i], wv[j], acc[i][j]);
        }
    }

    const int na = n0 + tj * 4;         // acc[i][0..3]
    const int nb = n0 + 64 + tj * 4;    // acc[i][4..7]
    const int ha = na >> 6, da = na & 63;
    const int hb = nb >> 6, db = nb & 63;
    float4 bfa = *(const float4*)&bias[na];
    float4 bfb = *(const float4*)&bias[nb];
    #pragma unroll
    for (int i = 0; i < 8; ++i) {
        int m = m0 + ti * 8 + i;
        int b = m >> 11, t = m & 2047;
        float4 v0, v1;
        v0.x = (acc[i][0] + bfa.x) * scale; v0.y = (acc[i][1] + bfa.y) * scale;
        v0.z = (acc[i][2] + bfa.z) * scale; v0.w = (acc[i][3] + bfa.w) * scale;
        v1.x = (acc[i][4] + bfb.x) * scale; v1.y = (acc[i][5] + bfb.y) * scale;
        v1.z = (acc[i][6] + bfb.z) * scale; v1.w = (acc[i][7] + bfb.w) * scale;
        *(float4*)&dst[((size_t)((b * NHEAD + ha) * T_LEN + t)) * HDIM + da] = v0;
        *(float4*)&dst[((size_t)((b * NHEAD + hb) * T_LEN + t)) * HDIM + db] = v1;
    }
}

// ---------------------------------------------------------------------------
// Kernel B1: count + compact distinct sampled indices (single block).
// ---------------------------------------------------------------------------
__global__ __launch_bounds__(256)
void count_compact_kernel(const int* __restrict__ idxs, int n,
                          int* __restrict__ count, int* __restrict__ klist,
                          int* __restrict__ ncp)
{
    __shared__ int cnt[T_LEN];
    __shared__ int th_tot[256];
    __shared__ int th_off[256];
    __shared__ int ncs;
    const int tid = threadIdx.x;
    for (int j = tid; j < T_LEN; j += 256) cnt[j] = 0;
    __syncthreads();
    for (int i = tid; i < n; i += 256) atomicAdd(&cnt[idxs[i] & (T_LEN - 1)], 1);
    __syncthreads();
    const int base = tid * 8;
    int flags[8]; int loc = 0;
    #pragma unroll
    for (int j = 0; j < 8; ++j) {
        int c = cnt[base + j];
        count[base + j] = c;
        flags[j] = (c > 0); loc += flags[j];
    }
    th_tot[tid] = loc;
    __syncthreads();
    if (tid == 0) {
        int run = 0;
        for (int i = 0; i < 256; ++i) { th_off[i] = run; run += th_tot[i]; }
        ncs = run;
        ncp[0] = run;
    }
    __syncthreads();
    int off = th_off[tid];
    #pragma unroll
    for (int j = 0; j < 8; ++j)
        if (flags[j]) klist[off++] = base + j;
    __syncthreads();
    const int nc = ncs;
    const int nt = (nc + 127) & ~127;
    const int k0 = klist[0];
    for (int j = nc + tid; j < nt; j += 256) klist[j] = k0;
}

// ---------------------------------------------------------------------------
// Kernel B2a: partial ksum/vsum per (bh, slice). Coalesced float4 streaming.
// ---------------------------------------------------------------------------
__global__ __launch_bounds__(256)
void ksum_vmean_part_kernel(const int* __restrict__ count,
                            const float* __restrict__ k, const float* __restrict__ v,
                            float* __restrict__ kpart, float* __restrict__ vpart)
{
    __shared__ int cs[256];
    alignas(16) __shared__ float rk[16 * 64];
    alignas(16) __shared__ float rv[16 * 64];

    const int sl = blockIdx.x, bh = blockIdx.y, tid = threadIdx.x;
    const int f4 = tid & 15, tg = tid >> 4;
    const int t0 = sl * 256;

    cs[tid] = count[t0 + tid];
    __syncthreads();

    const float4* k4 = (const float4*)(k + (size_t)bh * T_LEN * HDIM) + t0 * 16;
    const float4* v4 = (const float4*)(v + (size_t)bh * T_LEN * HDIM) + t0 * 16;

    float4 ak = {0.f, 0.f, 0.f, 0.f}, av = {0.f, 0.f, 0.f, 0.f};
    #pragma unroll
    for (int s = 0; s < 16; ++s) {
        int t = tg + s * 16;
        float c = (float)cs[t];
        float4 kf = k4[t * 16 + f4];
        float4 vf = v4[t * 16 + f4];
        ak.x = fmaf(c, kf.x, ak.x); ak.y = fmaf(c, kf.y, ak.y);
        ak.z = fmaf(c, kf.z, ak.z); ak.w = fmaf(c, kf.w, ak.w);
        av.x += vf.x; av.y += vf.y; av.z += vf.z; av.w += vf.w;
    }
    *(float4*)&rk[tg * 64 + f4 * 4] = ak;
    *(float4*)&rv[tg * 64 + f4 * 4] = av;
    __syncthreads();

    if (tid < 64) {
        float sk = 0.f, sv = 0.f;
        #pragma unroll
        for (int g = 0; g < 16; ++g) { sk += rk[g * 64 + tid]; sv += rv[g * 64 + tid]; }
        kpart[((size_t)bh * 8 + sl) * 64 + tid] = sk;
        vpart[((size_t)bh * 8 + sl) * 64 + tid] = sv;
    }
}

// ---------------------------------------------------------------------------
// Kernel B2b: reduce 8 slice-partials -> ksum[bh][d], vmean[bh][d].
// ---------------------------------------------------------------------------
__global__ __launch_bounds__(64)
void ksum_vmean_reduce_kernel(const float* __restrict__ kpart, const float* __restrict__ vpart,
                              float* __restrict__ ksum, float* __restrict__ vmean)
{
    const int bh = blockIdx.x, d = threadIdx.x;
    float sk = 0.f, sv = 0.f;
    #pragma unroll
    for (int sl = 0; sl < 8; ++sl) {
        sk += kpart[((size_t)bh * 8 + sl) * 64 + d];
        sv += vpart[((size_t)bh * 8 + sl) * 64 + d];
    }
    ksum[bh * 64 + d]  = sk;
    vmean[bh * 64 + d] = sv * (1.0f / 2048.0f);
}

// ---------------------------------------------------------------------------
// Kernel C: sparsity scan over compacted sampled keys (fp32, 128x128 tile).
// ---------------------------------------------------------------------------
__global__ __launch_bounds__(256)
void sparsity_scan_kernel(const float* __restrict__ q, const float* __restrict__ k,
                          const float* __restrict__ ksum, const int* __restrict__ klist,
                          const int* __restrict__ ncp, float* __restrict__ spars)
{
    alignas(16) __shared__ float qs[64 * 128];   // [d][qq]
    alignas(16) __shared__ float ks[64 * 128];   // [d][kk] (reused as reduce buf)
    __shared__ float ksm[64];

    const int tid = threadIdx.x;
    const int bh = blockIdx.y;
    const int q0 = blockIdx.x * 128;
    const int ti = tid >> 4, tj = tid & 15;

    const float* qb = q + ((size_t)bh * T_LEN + q0) * HDIM;
    const float* kb = k + (size_t)bh * T_LEN * HDIM;
    const int ntiles = (ncp[0] + 127) >> 7;

    #pragma unroll
    for (int s = 0; s < 8; ++s) {
        int u = tid + 256 * s;
        int qq = u & 127, c4 = u >> 7;
        float4 f = *(const float4*)&qb[qq * HDIM + c4 * 4];
        qs[(c4 * 4 + 0) * 128 + qq] = f.x;
        qs[(c4 * 4 + 1) * 128 + qq] = f.y;
        qs[(c4 * 4 + 2) * 128 + qq] = f.z;
        qs[(c4 * 4 + 3) * 128 + qq] = f.w;
    }
    if (tid < 64) ksm[tid] = ksum[bh * 64 + tid];

    float vmax[8];
    #pragma unroll
    for (int i = 0; i < 8; ++i) vmax[i] = -INFINITY;

    for (int kt = 0; kt < ntiles; ++kt) {
        __syncthreads();
        #pragma unroll
        for (int s = 0; s < 8; ++s) {
            int u = tid + 256 * s;
            int kk = u & 127, c4 = u >> 7;
            int row = klist[kt * 128 + kk];
            float4 f = *(const float4*)&kb[row * HDIM + c4 * 4];
            ks[(c4 * 4 + 0) * 128 + kk] = f.x;
            ks[(c4 * 4 + 1) * 128 + kk] = f.y;
            ks[(c4 * 4 + 2) * 128 + kk] = f.z;
            ks[(c4 * 4 + 3) * 128 + kk] = f.w;
        }
        __syncthreads();

        float dot[8][8];
        #pragma unroll
        for (int i = 0; i < 8; ++i)
            #pragma unroll
            for (int j = 0; j < 8; ++j) dot[i][j] = 0.0f;

        #pragma unroll 4
        for (int d = 0; d < 64; ++d) {
            float4 qa = *(const float4*)&qs[d * 128 + ti * 8];
            float4 qc = *(const float4*)&qs[d * 128 + ti * 8 + 4];
            float4 ka = *(const float4*)&ks[d * 128 + tj * 4];
            float4 kc = *(const float4*)&ks[d * 128 + 64 + tj * 4];
            float qv[8] = {qa.x, qa.y, qa.z, qa.w, qc.x, qc.y, qc.z, qc.w};
            float kv[8] = {ka.x, ka.y, ka.z, ka.w, kc.x, kc.y, kc.z, kc.w};
            #pragma unroll
            for (int i = 0; i < 8; ++i)
                #pragma unroll
                for (int j = 0; j < 8; ++j)
                    dot[i][j] = fmaf(qv[i], kv[j], dot[i][j]);
        }
        #pragma unroll
        for (int i = 0; i < 8; ++i) {
            float m8 = dot[i][0];
            #pragma unroll
            for (int j = 1; j < 8; ++j) m8 = fmaxf(m8, dot[i][j]);
            vmax[i] = fmaxf(vmax[i], m8);
        }
    }
    __syncthreads();

    float* red = ks;
    #pragma unroll
    for (int i = 0; i < 8; ++i) red[(ti * 8 + i) * 17 + tj] = vmax[i];
    __syncthreads();
    if (tid < 128) {
        float m = red[tid * 17];
        #pragma unroll
        for (int j = 1; j < 16; ++j) m = fmaxf(m, red[tid * 17 + j]);
        float sdot = 0.f;
        #pragma unroll
        for (int d = 0; d < 64; ++d) sdot = fmaf(qs[d * 128 + tid], ksm[d], sdot);
        spars[bh * T_LEN + q0 + tid] = m - sdot * (1.0f / 2048.0f);
    }
}

// ---------------------------------------------------------------------------
// Kernel D: top-40 per bh by iterative argmax (ties -> smaller index).
// ---------------------------------------------------------------------------
__global__ __launch_bounds__(256)
void topk_kernel(const float* __restrict__ spars, int* __restrict__ topi)
{
    __shared__ float vals[T_LEN];
    __shared__ float rv[256];
    __shared__ int   ri[256];
    const int bh = blockIdx.x, tid = threadIdx.x;
    for (int j = tid; j < T_LEN; j += 256) vals[j] = spars[bh * T_LEN + j];
    __syncthreads();
    for (int it = 0; it < USEL; ++it) {
        float bv = -INFINITY; int bi = 0;
        #pragma unroll
        for (int jj = 0; jj < 8; ++jj) {
            int j = tid * 8 + jj;
            float vv = vals[j];
            if (vv > bv) { bv = vv; bi = j; }
        }
        rv[tid] = bv; ri[tid] = bi;
        __syncthreads();
        for (int s = 128; s > 0; s >>= 1) {
            if (tid < s) {
                float ov = rv[tid + s]; int oi = ri[tid + s];
                if (ov > rv[tid] || (ov == rv[tid] && oi < ri[tid])) { rv[tid] = ov; ri[tid] = oi; }
            }
            __syncthreads();
        }
        if (tid == 0) {
            int win = ri[0] & (T_LEN - 1);
            topi[bh * USEL + it] = win;
            vals[win] = -INFINITY;
        }
        __syncthreads();
    }
}

// ---------------------------------------------------------------------------
// Kernel E1: gather selected q rows -> qsel[bh][u][d]. (q dead afterwards)
// ---------------------------------------------------------------------------
__global__ __launch_bounds__(256)
void gather_q_kernel(const float* __restrict__ q, const int* __restrict__ topi,
                     float* __restrict__ qsel)
{
    const int bh = blockIdx.x, tid = threadIdx.x;
    for (int i = tid; i < USEL * HDIM; i += 256) {
        int u = i >> 6, d = i & 63;
        int t = topi[bh * USEL + u] & (T_LEN - 1);
        qsel[(size_t)bh * USEL * HDIM + i] = q[((size_t)bh * T_LEN + t) * HDIM + d];
    }
}

// ---------------------------------------------------------------------------
// Kernel E2: S[bh][u][t] = qsel[bh][u] . k[bh][t]. Grid (8 t-slices, 32 bh).
// ---------------------------------------------------------------------------
__global__ __launch_bounds__(256)
void sel_scores_kernel(const float* __restrict__ qsel, const float* __restrict__ k,
                       float* __restrict__ S)
{
    __shared__ float qsT[64 * 41];    // [d][u] stride 41
    __shared__ float ksT[64 * 257];   // [d][t] stride 257

    const int sl = blockIdx.x, bh = blockIdx.y, tid = threadIdx.x;
    const int t0 = sl * 256;

    for (int i = tid; i < USEL * HDIM; i += 256) {
        int u = i >> 6, d = i & 63;
        qsT[d * 41 + u] = qsel[(size_t)bh * USEL * HDIM + i];
    }
    const float4* k4 = (const float4*)(k + (size_t)bh * T_LEN * HDIM);
    #pragma unroll
    for (int s = 0; s < 16; ++s) {
        int u = tid + 256 * s;          // 0..4095
        int c4 = u & 15, t = u >> 4;    // t 0..255
        float4 f = k4[(t0 + t) * 16 + c4];
        ksT[(c4 * 4 + 0) * 257 + t] = f.x;
        ksT[(c4 * 4 + 1) * 257 + t] = f.y;
        ksT[(c4 * 4 + 2) * 257 + t] = f.z;
        ksT[(c4 * 4 + 3) * 257 + t] = f.w;
    }
    __syncthreads();

    const int qg = tid >> 5;   // 0..7 -> 5 queries each
    const int kg = tid & 31;   // strided keys: kg + 32*j

    float acc[5][8];
    #pragma unroll
    for (int i = 0; i < 5; ++i)
        #pragma unroll
        for (int j = 0; j < 8; ++j) acc[i][j] = 0.0f;

    #pragma unroll 4
    for (int d = 0; d < 64; ++d) {
        float qv[5], kv[8];
        #pragma unroll
        for (int i = 0; i < 5; ++i) qv[i] = qsT[d * 41 + qg * 5 + i];
        #pragma unroll
        for (int j = 0; j < 8; ++j) kv[j] = ksT[d * 257 + kg + 32 * j];
        #pragma unroll
        for (int i = 0; i < 5; ++i)
            #pragma unroll
            for (int j = 0; j < 8; ++j)
                acc[i][j] = fmaf(qv[i], kv[j], acc[i][j]);
    }

    #pragma unroll
    for (int i = 0; i < 5; ++i) {
        float* sp = &S[((size_t)bh * USEL + qg * 5 + i) * T_LEN + t0 + kg];
        #pragma unroll
        for (int j = 0; j < 8; ++j) sp[32 * j] = acc[i][j];
    }
}

// ---------------------------------------------------------------------------
// Kernel E3: in-place softmax over each S row (1280 rows of 2048).
// ---------------------------------------------------------------------------
__global__ __launch_bounds__(256)
void sel_softmax_kernel(float* __restrict__ S)
{
    __shared__ float red[256];
    const int row = blockIdx.x, tid = threadIdx.x;
    float* sr = S + (size_t)row * T_LEN;

    float x[8];
    float m = -INFINITY;
    #pragma unroll
    for (int s = 0; s < 8; ++s) { x[s] = sr[tid + 256 * s]; m = fmaxf(m, x[s]); }
    red[tid] = m;
    __syncthreads();
    for (int s = 128; s > 0; s >>= 1) {
        if (tid < s) red[tid] = fmaxf(red[tid], red[tid + s]);
        __syncthreads();
    }
    m = red[0];
    __syncthreads();

    float sum = 0.f;
    #pragma unroll
    for (int s = 0; s < 8; ++s) { x[s] = __expf(x[s] - m); sum += x[s]; }
    red[tid] = sum;
    __syncthreads();
    for (int s = 128; s > 0; s >>= 1) {
        if (tid < s) red[tid] += red[tid + s];
        __syncthreads();
    }
    float inv = 1.0f / red[0];
    #pragma unroll
    for (int s = 0; s < 8; ++s) sr[tid + 256 * s] = x[s] * inv;
}

// ---------------------------------------------------------------------------
// Kernel E4: PV partial. Grid (16 t-slices, 32 bh).
// ---------------------------------------------------------------------------
__global__ __launch_bounds__(256)
void pv_part_kernel(const float* __restrict__ S, const float* __restrict__ v,
                    float* __restrict__ part)
{
    __shared__ float ps[USEL * 128];      // [q][t]
    __shared__ float vs[128 * 69];        // [t][d] stride 69
    __shared__ float obuf[128 * 20];

    const int sl = blockIdx.x, bh = blockIdx.y, tid = threadIdx.x;
    const int t0 = sl * 128;

    for (int i = tid; i < USEL * 128; i += 256) {
        int q = i >> 7, t = i & 127;
        ps[q * 128 + t] = S[((size_t)bh * USEL + q) * T_LEN + t0 + t];
    }
    const float4* v4 = (const float4*)(v + (size_t)bh * T_LEN * HDIM);
    #pragma unroll
    for (int s = 0; s < 8; ++s) {
        int u = tid + 256 * s;          // 0..2047
        int c4 = u & 15, t = u >> 4;    // t 0..127
        float4 f = v4[(t0 + t) * 16 + c4];
        vs[t * 69 + c4 * 4 + 0] = f.x;
        vs[t * 69 + c4 * 4 + 1] = f.y;
        vs[t * 69 + c4 * 4 + 2] = f.z;
        vs[t * 69 + c4 * 4 + 3] = f.w;
    }
    __syncthreads();

    const int qg = tid >> 5, r = tid & 31;
    const int dg = r >> 1, th = r & 1;
    const int tb = th * 64;

    float o[5][4];
    #pragma unroll
    for (int i = 0; i < 5; ++i)
        #pragma unroll
        for (int j = 0; j < 4; ++j) o[i][j] = 0.0f;

    #pragma unroll 4
    for (int tt = 0; tt < 64; ++tt) {
        int t = tb + tt;
        float pv[5];
        #pragma unroll
        for (int i = 0; i < 5; ++i) pv[i] = ps[(qg * 5 + i) * 128 + t];
        float4 vv = *(const float4*)&vs[t * 69 + dg * 4];
        #pragma unroll
        for (int i = 0; i < 5; ++i) {
            o[i][0] = fmaf(pv[i], vv.x, o[i][0]);
            o[i][1] = fmaf(pv[i], vv.y, o[i][1]);
            o[i][2] = fmaf(pv[i], vv.z, o[i][2]);
            o[i][3] = fmaf(pv[i], vv.w, o[i][3]);
        }
    }

    const int p = qg * 16 + dg;   // 0..127
    if (th == 1) {
        #pragma unroll
        for (int i = 0; i < 5; ++i)
            #pragma unroll
            for (int j = 0; j < 4; ++j) obuf[p * 20 + i * 4 + j] = o[i][j];
    }
    __syncthreads();
    if (th == 0) {
        float* pb = part + ((size_t)bh * 16 + sl) * (USEL * HDIM);
        #pragma unroll
        for (int i = 0; i < 5; ++i)
            #pragma unroll
            for (int j = 0; j < 4; ++j)
                pb[(qg * 5 + i) * HDIM + dg * 4 + j] = o[i][j] + obuf[p * 20 + i * 4 + j];
    }
}

// ---------------------------------------------------------------------------
// Kernel E5: deterministic merge of 16 PV partials -> attn[bh][u][d].
// ---------------------------------------------------------------------------
__global__ __launch_bounds__(256)
void pv_merge_kernel(const float* __restrict__ part, float* __restrict__ attn)
{
    const int bh = blockIdx.x, tid = threadIdx.x;
    for (int i = tid; i < USEL * HDIM; i += 256) {
        float s = 0.f;
        #pragma unroll
        for (int sl = 0; sl < 16; ++sl)
            s += part[((size_t)bh * 16 + sl) * (USEL * HDIM) + i];
        attn[(size_t)bh * USEL * HDIM + i] = s;
    }
}

// ---------------------------------------------------------------------------
// Kernel F1: fill context (B,T,E layout, fp32) with per-head vmean.
// ---------------------------------------------------------------------------
__global__ __launch_bounds__(256)
void ctx_fill_kernel(const float* __restrict__ vmean, float* __restrict__ ctx)
{
    int flat = blockIdx.x * 256 + threadIdx.x;
    int d = flat & 63, h = (flat >> 6) & 7, b = flat >> 20;
    int bh = (b << 3) | h;
    ctx[flat] = vmean[bh * 64 + d];
}

// ---------------------------------------------------------------------------
// Kernel F2: scatter attn rows into context at top_idx positions.
// ---------------------------------------------------------------------------
__global__ void ctx_scatter_kernel(const float* __restrict__ attn, const int* __restrict__ topi,
                                   float* __restrict__ ctx)
{
    const int u = blockIdx.x, bh = blockIdx.y, d = threadIdx.x;
    const int b = bh >> 3, h = bh & 7;
    const int t = topi[bh * USEL + u] & (T_LEN - 1);
    ctx[(size_t)(b * T_LEN + t) * EMB + h * 64 + d] =
        attn[((size_t)bh * USEL + u) * HDIM + d];
}

// ---------------------------------------------------------------------------
// Kernel G: out = ctx @ Wo^T + bo via bf16 hi+lo 3-pass MFMA (16x16x32).
// 128x128 tile, BK=32. acc += Ah*Bh + Ah*Bl + Al*Bh (drop Al*Bl ~2^-18).
// u16 tiles stride 40 (16B-aligned fragments, 2-way banks). C/D layout:
// col=lane&15 (n), row=(lane>>4)*4+r (m). Output tolerance 4.3e-3 >> 1e-5 err.
// Selection path (q/k/topk) untouched by this change.
// ---------------------------------------------------------------------------
__global__ __launch_bounds__(256)
void out_proj_kernel(const float* __restrict__ A, const float* __restrict__ Wo,
                     const float* __restrict__ bo, float* __restrict__ out)
{
    alignas(16) __shared__ u16 Ah[128 * 40];
    alignas(16) __shared__ u16 Al[128 * 40];
    alignas(16) __shared__ u16 Bh[128 * 40];
    alignas(16) __shared__ u16 Bl[128 * 40];

    const int tid = threadIdx.x;
    const int m0 = blockIdx.x * 128;
    const int n0 = blockIdx.y * 128;
    const int w = tid >> 6, lane = tid & 63;
    const int wm = w & 1, wn = w >> 1;
    const int lm = lane & 15, kq = lane >> 4;

    f32x4 acc[4][4];
    #pragma unroll
    for (int i = 0; i < 4; ++i)
        #pragma unroll
        for (int j = 0; j < 4; ++j)
            #pragma unroll
            for (int r = 0; r < 4; ++r) acc[i][j][r] = 0.0f;

    for (int kc = 0; kc < EMB; kc += 32) {
        __syncthreads();
        #pragma unroll
        for (int s = 0; s < 4; ++s) {
            int u = tid + 256 * s;        // 0..1023
            int row = u >> 3, c4 = u & 7; // row 0..127, c4 0..7 (k-quad)
            float4 fa = *(const float4*)&A[(size_t)(m0 + row) * EMB + kc + c4 * 4];
            float4 fb = *(const float4*)&Wo[(n0 + row) * EMB + kc + c4 * 4];
            uint2 ph, pl;
            cvt4_hilo(fa, ph, pl);
            *(uint2*)&Ah[row * 40 + c4 * 4] = ph;
            *(uint2*)&Al[row * 40 + c4 * 4] = pl;
            cvt4_hilo(fb, ph, pl);
            *(uint2*)&Bh[row * 40 + c4 * 4] = ph;
            *(uint2*)&Bl[row * 40 + c4 * 4] = pl;
        }
        __syncthreads();

        bf16v8 ah[4], al[4], bh[4], bl[4];
        #pragma unroll
        for (int i = 0; i < 4; ++i) {
            int ra = (wm * 64 + i * 16 + lm) * 40 + kq * 8;
            ah[i] = *(const bf16v8*)&Ah[ra];
            al[i] = *(const bf16v8*)&Al[ra];
            int rb = (wn * 64 + i * 16 + lm) * 40 + kq * 8;
            bh[i] = *(const bf16v8*)&Bh[rb];
            bl[i] = *(const bf16v8*)&Bl[rb];
        }
        #pragma unroll
        for (int i = 0; i < 4; ++i)
            #pragma unroll
            for (int j = 0; j < 4; ++j) {
                acc[i][j] = __builtin_amdgcn_mfma_f32_16x16x32_bf16(ah[i], bh[j], acc[i][j], 0, 0, 0);
                acc[i][j] = __builtin_amdgcn_mfma_f32_16x16x32_bf16(ah[i], bl[j], acc[i][j], 0, 0, 0);
                acc[i][j] = __builtin_amdgcn_mfma_f32_16x16x32_bf16(al[i], bh[j], acc[i][j], 0, 0, 0);
            }
    }

    #pragma unroll
    for (int j = 0; j < 4; ++j) {
        int ng = n0 + wn * 64 + j * 16 + lm;
        float bias = bo[ng];
        #pragma unroll
        for (int i = 0; i < 4; ++i)
            #pragma unroll
            for (int r = 0; r < 4; ++r) {
                int mg = m0 + wm * 64 + i * 16 + kq * 4 + r;
                out[(size_t)mg * EMB + ng] = acc[i][j][r] + bias;
            }
    }
}

// ---------------------------------------------------------------------------
// Diagnostic: if ws_size is too small, report it via d_out (absmax ~= MiB).
// ---------------------------------------------------------------------------
__global__ __launch_bounds__(256)
void ws_diag_kernel(float* __restrict__ out, int n, float mib)
{
    int flat = blockIdx.x * 256 + threadIdx.x;
    if (flat < n) out[flat] = mib;
}

// ---------------------------------------------------------------------------
extern "C" void kernel_launch(void* const* d_in, const int* in_sizes, int n_in,
                              void* d_out, int out_size, void* d_ws, size_t ws_size,
                              hipStream_t stream)
{
    // fp32 inputs/outputs in dict order (confirmed). Bind by size; same-size
    // tensors in encounter (=dict) order: Wq, Wk, Wv, Wo.
    const float* X = nullptr; const int* idxs = nullptr;
    const float* Wseen[4] = {nullptr, nullptr, nullptr, nullptr};
    const float* bseen[4] = {nullptr, nullptr, nullptr, nullptr};
    int nw = 0, nb = 0, u_part = 2048;
    for (int i = 0; i < n_in; ++i) {
        int sz = in_sizes[i];
        if (sz == EMB * EMB * 16) { if (!X) X = (const float*)d_in[i]; }
        else if (sz == T_LEN)     { if (!idxs) { idxs = (const int*)d_in[i]; u_part = sz; } }
        else if (sz == EMB * EMB) { if (nw < 4) Wseen[nw++] = (const float*)d_in[i]; }
        else if (sz == EMB)       { if (nb < 4) bseen[nb++] = (const float*)d_in[i]; }
    }
    if (!X || !idxs || nw < 4 || nb < 4) {
        X = (const float*)d_in[0]; idxs = (const int*)d_in[1];
        Wseen[0] = (const float*)d_in[2]; bseen[0] = (const float*)d_in[3];
        Wseen[1] = (const float*)d_in[4]; bseen[1] = (const float*)d_in[5];
        Wseen[2] = (const float*)d_in[6]; bseen[2] = (const float*)d_in[7];
        Wseen[3] = (const float*)d_in[8]; bseen[3] = (const float*)d_in[9];
        u_part = in_sizes[1];
    }
    const float *Wq = Wseen[0], *Wk = Wseen[1], *Wv = Wseen[2], *Wo = Wseen[3];
    const float *bq = bseen[0], *bk = bseen[1], *bv = bseen[2], *bo = bseen[3];

    // Workspace layout (peak 50,951,168 B, unchanged).
    const size_t NEED = 50951168ULL;
    if (ws_size < NEED) {
        ws_diag_kernel<<<(out_size + 255) / 256, 256, 0, stream>>>(
            (float*)d_out, out_size, (float)(ws_size >> 20));
        return;
    }

    float* ws    = (float*)d_ws;
    float* qw    = ws;                    // 4,194,304 floats
    float* kw    = qw + 4194304;
    float* vw    = kw + 4194304;
    float* tail  = vw + 4194304;
    float* slotA = tail;                  // 81920: qsel, later attn
    float* spars = tail + 81920;          // 65536
    int*   count = (int*)(tail + 147456); // 2048
    float* ksum  = tail + 149504;         // 2048
    float* vmean = tail + 151552;         // 2048
    int*   topi  = (int*)(tail + 153600); // 1280
    float* kpart = tail;                  // overlays in slotA (disjoint liveness)
    float* vpart = tail + 16384;
    int*   klist = (int*)(tail + 32768);
    int*   ncp   = (int*)(tail + 34816);
    float* S     = qw;                    // q dead after gather
    float* pvp   = qw + 2621440;
    float* qsel  = slotA;
    float* attn  = slotA;
    float* ctx   = (float*)d_ws;

    qkv_proj_kernel<<<dim3(64, 4, 3), 256, 0, stream>>>(X, Wq, bq, Wk, bk, Wv, bv, qw, kw, vw);
    count_compact_kernel<<<1, 256, 0, stream>>>(idxs, u_part, count, klist, ncp);
    ksum_vmean_part_kernel<<<dim3(8, 32), 256, 0, stream>>>(count, kw, vw, kpart, vpart);
    ksum_vmean_reduce_kernel<<<32, 64, 0, stream>>>(kpart, vpart, ksum, vmean);
    sparsity_scan_kernel<<<dim3(16, 32), 256, 0, stream>>>(qw, kw, ksum, klist, ncp, spars);
    topk_kernel<<<32, 256, 0, stream>>>(spars, topi);
    gather_q_kernel<<<32, 256, 0, stream>>>(qw, topi, qsel);
    // qw dead; S/pvp take over that region.
    sel_scores_kernel<<<dim3(8, 32), 256, 0, stream>>>(qsel, kw, S);
    sel_softmax_kernel<<<1280, 256, 0, stream>>>(S);
    pv_part_kernel<<<dim3(16, 32), 256, 0, stream>>>(S, vw, pvp);
    pv_merge_kernel<<<32, 256, 0, stream>>>(pvp, attn);
    // S/pvp dead; ctx takes over the whole front region.
    ctx_fill_kernel<<<16384, 256, 0, stream>>>(vmean, ctx);
    ctx_scatter_kernel<<<dim3(USEL, BHEADS), 64, 0, stream>>>(attn, topi, ctx);
    out_proj_kernel<<<dim3(64, 4), 256, 0, stream>>>(ctx, Wo, bo, (float*)d_out);
}